// Round 11
// baseline (315.996 us; speedup 1.0000x reference)
//
#include <hip/hip_runtime.h>
#include <hip/hip_bf16.h>

#define N_PTS 100000
#define KOFF 343
#define EPS 1e-5f
#define NTILES 3125    // N_PTS / 32
#define SSTR 173       // odd stage stride -> conflict-free idx reads

typedef __hip_bfloat16 bf16;
typedef __attribute__((ext_vector_type(4))) float f32x4;
typedef __attribute__((ext_vector_type(8))) short s16x8;

// ---------------- pack: w_conv [343][32][32] f32 -> bf16 B-fragments (16x16x32) ----------------
// wpk[k][cn][lane][j] = w_conv[k][ (lane>>4)*8 + j ][ cn*16 + (lane&15) ]
__global__ __launch_bounds__(256) void pack_kernel(const float* __restrict__ w_conv,
                                                   bf16* __restrict__ wpk) {
  int t = blockIdx.x * 256 + threadIdx.x;
  if (t >= KOFF * 128) return;
  int l = t & 63;
  int cn = (t >> 6) & 1;
  int k = t >> 7;
  int rr = l & 15;
  int q = l >> 4;
  const float* wk = w_conv + k * 1024;
  s16x8 v;
  for (int j = 0; j < 8; ++j) {
    bf16 h = __float2bfloat16(wk[(q * 8 + j) * 32 + cn * 16 + rr]);
    short sv;
    __builtin_memcpy(&sv, &h, 2);
    v[j] = sv;
  }
  *reinterpret_cast<s16x8*>(reinterpret_cast<char*>(wpk) + (size_t)t * 16) = v;
}

// ---------------- unary1: h1b = bf16( LN(feats @ w1) )  [N,32] ----------------
__global__ __launch_bounds__(256) void unary1_kernel(const float* __restrict__ feats,
    const float* __restrict__ w1, const float* __restrict__ g1,
    const float* __restrict__ b1, bf16* __restrict__ h1b) {
  __shared__ float sf[8][128];
  __shared__ float sw[128 * 32];
  int tid = threadIdx.x;
  int rbase = blockIdx.x * 8;
  for (int i = tid; i < 1024; i += 256)
    reinterpret_cast<f32x4*>(sw)[i] = reinterpret_cast<const f32x4*>(w1)[i];
  {
    int i = tid;
    int r = rbase + (i >> 5);
    f32x4 v = reinterpret_cast<const f32x4*>(feats)[(size_t)r * 32 + (i & 31)];
    reinterpret_cast<f32x4*>(&sf[0][0])[i] = v;
  }
  __syncthreads();
  int half = tid >> 5;
  int c = tid & 31;
  int r = rbase + half;
  const float* frow = sf[half];
  float acc = 0.f;
  #pragma unroll 8
  for (int kk = 0; kk < 128; ++kk)
    acc += frow[kk] * sw[kk * 32 + c];
  float s = acc, s2 = acc * acc;
  #pragma unroll
  for (int m = 16; m >= 1; m >>= 1) {
    s  += __shfl_xor(s,  m, 64);
    s2 += __shfl_xor(s2, m, 64);
  }
  float mean = s * (1.f / 32.f);
  float var  = s2 * (1.f / 32.f) - mean * mean;
  float y = (acc - mean) * rsqrtf(var + EPS) * g1[c] + b1[c];
  h1b[(size_t)r * 32 + c] = __float2bfloat16(y);
}

// ---------------- conv v7: 16x16x32 MFMA (1 TA line-touch per h1 row) ----------------
// Block = 256 thr = 4 waves, one 32-point tile, k-split x4, 2-round idx staging
// (22.1 KB LDS). Per offset: A(pm0)+A(pm1) instrs touch 16 lines each (4 lanes/line,
// row read once) vs 32 with the 32x32 shape. 4 MFMAs/offset into 4 f32x4 accs.
// A: row=lane&15, k=(lane>>4)*8+j ; B: col=lane&15, k=(lane>>4)*8+j
// D: col=lane&15, row=(lane>>4)*4+reg   [16x16 mapping, m89-verified]
template<int KCNT, int KBASE>
__device__ __forceinline__ void process_round(const int* __restrict__ snbr,
    const bf16* __restrict__ h1b, const s16x8* __restrict__ wb,
    f32x4& acc00, f32x4& acc01, f32x4& acc10, f32x4& acc11, int wave, int l) {
  int k0 = (KCNT * wave) >> 2;
  int k1 = (KCNT * (wave + 1)) >> 2;
  int rr = l & 15;
  int q = l >> 4;
  const int* row0 = snbr + rr * SSTR;          // idx row for point rr      (pm=0)
  const int* row1 = snbr + (16 + rr) * SSTR;   // idx row for point 16+rr   (pm=1)
  const s16x8* h1s8 = reinterpret_cast<const s16x8*>(h1b);
  const s16x8 zv = {0, 0, 0, 0, 0, 0, 0, 0};
  for (int kb = k0; kb < k1; kb += 4) {
    int id0[4], id1[4];
    s16x8 A0[4], A1[4], B0[4], B1[4];
    #pragma unroll
    for (int j = 0; j < 4; ++j) {
      int k = kb + j;
      id0[j] = (k < k1) ? row0[k] : -1;
      id1[j] = (k < k1) ? row1[k] : -1;
    }
    #pragma unroll
    for (int j = 0; j < 4; ++j) {
      int k = kb + j;
      int kc = (k < k1) ? k : (k1 - 1);
      A0[j] = h1s8[(size_t)(id0[j] < 0 ? 0 : id0[j]) * 4 + q];
      A1[j] = h1s8[(size_t)(id1[j] < 0 ? 0 : id1[j]) * 4 + q];
      B0[j] = wb[(size_t)(KBASE + kc) * 128 + l];        // cn=0 fragment
      B1[j] = wb[(size_t)(KBASE + kc) * 128 + 64 + l];   // cn=1 fragment
    }
    #pragma unroll
    for (int j = 0; j < 4; ++j) {
      s16x8 a0 = id0[j] < 0 ? zv : A0[j];
      s16x8 a1 = id1[j] < 0 ? zv : A1[j];
      acc00 = __builtin_amdgcn_mfma_f32_16x16x32_bf16(a0, B0[j], acc00, 0, 0, 0);
      acc01 = __builtin_amdgcn_mfma_f32_16x16x32_bf16(a0, B1[j], acc01, 0, 0, 0);
      acc10 = __builtin_amdgcn_mfma_f32_16x16x32_bf16(a1, B0[j], acc10, 0, 0, 0);
      acc11 = __builtin_amdgcn_mfma_f32_16x16x32_bf16(a1, B1[j], acc11, 0, 0, 0);
    }
  }
}

__global__ __launch_bounds__(256) void conv16_kernel(const bf16* __restrict__ h1b,
    const int* __restrict__ nbr, const bf16* __restrict__ wpk,
    float* __restrict__ h2) {
  __shared__ int sbuf[32 * SSTR];         // 22,144 B; reused as float red[4096] (16 KB)
  int tid = threadIdx.x;
  int wave = tid >> 6;
  int l = tid & 63;
  int pbase = blockIdx.x * 32;
  const int* g = nbr + (size_t)pbase * KOFF;
  const s16x8* wb = reinterpret_cast<const s16x8*>(wpk);
  f32x4 acc00 = {0.f, 0.f, 0.f, 0.f}, acc01 = {0.f, 0.f, 0.f, 0.f};
  f32x4 acc10 = {0.f, 0.f, 0.f, 0.f}, acc11 = {0.f, 0.f, 0.f, 0.f};

  // round 1: offsets [0,172)
  for (int i = tid; i < 32 * 172; i += 256) {
    int row = i / 172;                    // const divisor -> magic mul
    int kk = i - row * 172;
    sbuf[row * SSTR + kk] = g[row * KOFF + kk];
  }
  __syncthreads();
  process_round<172, 0>(sbuf, h1b, wb, acc00, acc01, acc10, acc11, wave, l);
  __syncthreads();
  // round 2: offsets [172,343)
  for (int i = tid; i < 32 * 171; i += 256) {
    int row = i / 171;
    int kk = i - row * 171;
    sbuf[row * SSTR + kk] = g[row * KOFF + 172 + kk];
  }
  __syncthreads();
  process_round<171, 172>(sbuf, h1b, wb, acc00, acc01, acc10, acc11, wave, l);
  __syncthreads();

  // reduction: D row = (lane>>4)*4 + reg, col = lane&15; pm adds +16 rows, cn +16 cols
  float* red = reinterpret_cast<float*>(sbuf);
  int rr = l & 15;
  int q = l >> 4;
  #pragma unroll
  for (int reg = 0; reg < 4; ++reg) {
    int prow = q * 4 + reg;
    red[wave * 1024 + prow * 32 + rr]             = acc00[reg];
    red[wave * 1024 + prow * 32 + 16 + rr]        = acc01[reg];
    red[wave * 1024 + (16 + prow) * 32 + rr]      = acc10[reg];
    red[wave * 1024 + (16 + prow) * 32 + 16 + rr] = acc11[reg];
  }
  __syncthreads();
  const f32x4* rv = reinterpret_cast<const f32x4*>(red);
  f32x4 s = rv[tid] + rv[256 + tid] + rv[512 + tid] + rv[768 + tid];
  reinterpret_cast<f32x4*>(h2 + (size_t)pbase * 32)[tid] = s;
}

// ---------------- unary2 v2: out = gelu(LN(h2 @ w2)) + feats, 2 rows/wave ----------------
__global__ __launch_bounds__(256) void unary2_kernel(const float* __restrict__ h2,
    const float* __restrict__ w2, const float* __restrict__ g2,
    const float* __restrict__ b2, const float* __restrict__ feats,
    float* __restrict__ out) {
  int tid = threadIdx.x;
  int wave = tid >> 6;
  int l = tid & 63;
  int r0 = blockIdx.x * 8 + wave * 2;     // rows r0, r0+1
  const f32x4* h0 = reinterpret_cast<const f32x4*>(h2 + (size_t)r0 * 32);
  const f32x4* h1r = reinterpret_cast<const f32x4*>(h2 + (size_t)(r0 + 1) * 32);
  float a00 = 0.f, a01 = 0.f, a10 = 0.f, a11 = 0.f;
  #pragma unroll
  for (int q = 0; q < 8; ++q) {
    f32x4 v0 = h0[q];
    f32x4 v1 = h1r[q];
    #pragma unroll
    for (int j = 0; j < 4; ++j) {
      int kk = q * 4 + j;
      float wlo = w2[kk * 128 + l];
      float whi = w2[kk * 128 + 64 + l];
      a00 += v0[j] * wlo;  a01 += v0[j] * whi;
      a10 += v1[j] * wlo;  a11 += v1[j] * whi;
    }
  }
  float s0 = a00 + a01, q0 = a00 * a00 + a01 * a01;
  float s1 = a10 + a11, q1 = a10 * a10 + a11 * a11;
  #pragma unroll
  for (int m = 32; m >= 1; m >>= 1) {
    s0 += __shfl_xor(s0, m, 64);
    q0 += __shfl_xor(q0, m, 64);
    s1 += __shfl_xor(s1, m, 64);
    q1 += __shfl_xor(q1, m, 64);
  }
  float m0 = s0 * (1.f / 128.f);
  float v0 = q0 * (1.f / 128.f) - m0 * m0;
  float i0 = rsqrtf(v0 + EPS);
  float m1 = s1 * (1.f / 128.f);
  float v1 = q1 * (1.f / 128.f) - m1 * m1;
  float i1 = rsqrtf(v1 + EPS);
  float glo = g2[l], ghi = g2[64 + l];
  float blo = b2[l], bhi = b2[64 + l];
  float y00 = (a00 - m0) * i0 * glo + blo;
  float y01 = (a01 - m0) * i0 * ghi + bhi;
  float y10 = (a10 - m1) * i1 * glo + blo;
  float y11 = (a11 - m1) * i1 * ghi + bhi;
  float e00 = 0.5f * y00 * (1.f + erff(y00 * 0.70710678118f));
  float e01 = 0.5f * y01 * (1.f + erff(y01 * 0.70710678118f));
  float e10 = 0.5f * y10 * (1.f + erff(y10 * 0.70710678118f));
  float e11 = 0.5f * y11 * (1.f + erff(y11 * 0.70710678118f));
  out[(size_t)r0 * 128 + l]            = e00 + feats[(size_t)r0 * 128 + l];
  out[(size_t)r0 * 128 + 64 + l]       = e01 + feats[(size_t)r0 * 128 + 64 + l];
  out[(size_t)(r0 + 1) * 128 + l]      = e10 + feats[(size_t)(r0 + 1) * 128 + l];
  out[(size_t)(r0 + 1) * 128 + 64 + l] = e11 + feats[(size_t)(r0 + 1) * 128 + 64 + l];
}

extern "C" void kernel_launch(void* const* d_in, const int* in_sizes, int n_in,
                              void* d_out, int out_size, void* d_ws, size_t ws_size,
                              hipStream_t stream) {
  const float* feats  = (const float*)d_in[0];
  const int*   nbr    = (const int*)d_in[1];
  const float* w1     = (const float*)d_in[2];
  const float* ln1_g  = (const float*)d_in[3];
  const float* ln1_b  = (const float*)d_in[4];
  const float* w_conv = (const float*)d_in[5];
  const float* w2     = (const float*)d_in[6];
  const float* ln2_g  = (const float*)d_in[7];
  const float* ln2_b  = (const float*)d_in[8];
  float* out = (float*)d_out;
  char* ws = (char*)d_ws;
  bf16*  h1b = (bf16*)ws;                    // 100000*32*2  = 6,400,000 B
  bf16*  wpk = (bf16*)(ws + 6400000);        // 343*128*16   =   702,464 B
  float* h2  = (float*)(ws + 7102464);       // 100000*32*4  = 12,800,000 B

  hipLaunchKernelGGL(pack_kernel,    dim3((KOFF * 128 + 255) / 256), dim3(256), 0, stream, w_conv, wpk);
  hipLaunchKernelGGL(unary1_kernel,  dim3(N_PTS / 8),                dim3(256), 0, stream, feats, w1, ln1_g, ln1_b, h1b);
  hipLaunchKernelGGL(conv16_kernel,  dim3(NTILES),                   dim3(256), 0, stream, h1b, nbr, wpk, h2);
  hipLaunchKernelGGL(unary2_kernel,  dim3(N_PTS / 8),                dim3(256), 0, stream, h2, w2, ln2_g, ln2_b, feats, out);
}